// Round 7
// baseline (1627.336 us; speedup 1.0000x reference)
//
#include <hip/hip_runtime.h>

#define TH 30
#define NT 256

typedef short bf16x8 __attribute__((ext_vector_type(8)));
typedef float f32x4 __attribute__((ext_vector_type(4)));
typedef unsigned short u16x4 __attribute__((ext_vector_type(4)));
typedef unsigned int u32x4 __attribute__((ext_vector_type(4)));

// split f into bf16 hi + bf16 lo (truncation; lo compensates) ~2^-17 rel
__device__ __forceinline__ void f2hl(float f, unsigned short& h, unsigned short& l) {
  unsigned int ub = __float_as_uint(f);
  h = (unsigned short)(ub >> 16);
  float fh = __uint_as_float(ub & 0xffff0000u);
  l = (unsigned short)(__float_as_uint(f - fh) >> 16);
}
__device__ __forceinline__ float rec(unsigned short h, unsigned short l) {
  return __uint_as_float((unsigned int)h << 16) + __uint_as_float((unsigned int)l << 16);
}
// [R][64] ushort, granule-swizzled: (r,k) at r*64 + (((k>>3)^(r&7))<<3) + (k&7)
__device__ __forceinline__ bf16x8 ld64(const unsigned short* buf, int row, int kcg) {
  return *(const bf16x8*)(buf + row * 64 + ((kcg ^ (row & 7)) << 3));
}
__device__ __forceinline__ void st64_4(unsigned short* buf, int row, int col0, u16x4 v) {
  *(u16x4*)(buf + row * 64 + (((col0 >> 3) ^ (row & 7)) << 3) + (col0 & 7)) = v;
}
// K=16 tiles, stride 16; g>=2 -> zero frags (K padding)
__device__ __forceinline__ bf16x8 ld16s(const unsigned short* buf, int row, int g) {
  if (g < 2) return *(const bf16x8*)(buf + row * 16 + (g << 3));
  bf16x8 z = {};
  return z;
}
__device__ __forceinline__ void st16s(unsigned short* buf, int row, int col0, u16x4 v) {
  *(u16x4*)(buf + row * 16 + col0) = v;
}
__device__ __forceinline__ void cvt4(f32x4 a, u16x4& h, u16x4& l) {
  #pragma unroll
  for (int i = 0; i < 4; ++i) {
    unsigned short hh, ll;
    f2hl(a[i], hh, ll);
    h[i] = hh; l[i] = ll;
  }
}
__device__ __forceinline__ bf16x8 negbf(bf16x8 v) {
  u32x4 u = __builtin_bit_cast(u32x4, v);
  u ^= 0x80008000u;
  return __builtin_bit_cast(bf16x8, u);
}

#define MFMA3(ACC, XH, XL, YH, YL)                                        \
  ACC = __builtin_amdgcn_mfma_f32_16x16x32_bf16(XH, YH, ACC, 0, 0, 0);    \
  ACC = __builtin_amdgcn_mfma_f32_16x16x32_bf16(XH, YL, ACC, 0, 0, 0);    \
  ACC = __builtin_amdgcn_mfma_f32_16x16x32_bf16(XL, YH, ACC, 0, 0, 0);

// LDS plan (bytes; total 45760 -> ~46080 alloc -> 3 blocks/CU with 22KB margin)
#define O_VH   0       /* 8192  V hi (sym), swz */
#define O_VL   8192    /* 8192  V lo */
#define O_WTH  16384   /* 8192  Wt hi, swz (init: At staging, then goals rows 0..31) */
#define O_WTL  24576   /* 8192  Wt lo */
#define O_VBH  32768   /* 2048  VBt hi (init: Bt staging) */
#define O_VBL  34816   /* 2048  VBt lo */
#define O_BWH  36864   /* 2048  BtWt hi; St in-place */
#define O_BWL  38912   /* 2048  lo */
#define O_MTH  40960   /* 512   Mt[u][i]=M[i][u] hi */
#define O_MTL  41472
#define O_MBH  41984   /* 512   Mb[u][w]=M[u][w] hi */
#define O_MBL  42496
#define O_VUU  43008   /* f32 16x17 */
#define O_MT   44096   /* f32 16x17 */
#define O_VP   45184   /* f32 64  A^T v */
#define O_SV   45440   /* f32 64  v */
#define O_BTV  45696   /* f32 16  B^T v */
#define SMEM_BYTES 45760

__global__ __launch_bounds__(NT, 3) void lqr6(
    const float* __restrict__ gA, const float* __restrict__ gB,
    const float* __restrict__ gQ, const float* __restrict__ gR,
    const float* __restrict__ gG, float* __restrict__ gOut,
    float* __restrict__ gQG, int qgSlot, int bsz)
{
  __shared__ __align__(16) unsigned char smem[SMEM_BYTES];
  unsigned short* sVh  = (unsigned short*)(smem + O_VH);
  unsigned short* sVl  = (unsigned short*)(smem + O_VL);
  unsigned short* sWth = (unsigned short*)(smem + O_WTH);
  unsigned short* sWtl = (unsigned short*)(smem + O_WTL);
  unsigned short* sVBh = (unsigned short*)(smem + O_VBH);
  unsigned short* sVBl = (unsigned short*)(smem + O_VBL);
  unsigned short* sBWh = (unsigned short*)(smem + O_BWH);
  unsigned short* sBWl = (unsigned short*)(smem + O_BWL);
  unsigned short* sMth = (unsigned short*)(smem + O_MTH);
  unsigned short* sMtl = (unsigned short*)(smem + O_MTL);
  unsigned short* sMbh = (unsigned short*)(smem + O_MBH);
  unsigned short* sMbl = (unsigned short*)(smem + O_MBL);
  float* sVuu = (float*)(smem + O_VUU);
  float* sMT  = (float*)(smem + O_MT);
  float* sVp  = (float*)(smem + O_VP);
  float* sv   = (float*)(smem + O_SV);
  float* sBtv = (float*)(smem + O_BTV);

  const int b    = blockIdx.x;
  const int tid  = threadIdx.x;
  const int lane = tid & 63;
  const int wv   = tid >> 6;      // 0..3
  const int r    = lane & 15;
  const int g    = lane >> 4;
  const int it   = wv;            // owned row-tile

  const float* Ab = gA + (size_t)b * 4096;
  const float* Bb = gB + (size_t)b * 1024;
  const float* Qb = gQ + (size_t)b * 4096;
  const float* Rb = gR + (size_t)b * 256;
  const float* Gb = gG + (size_t)b * ((TH + 1) * 64);

  // ---- S1: stage At h/l -> sWt (temp), Bt h/l -> sVB (temp) ----
  for (int idx = tid; idx < 4096; idx += NT) {
    int k = idx >> 6, i = idx & 63;
    unsigned short hh, ll;
    f2hl(Ab[idx], hh, ll);
    int off = i * 64 + (((k >> 3) ^ (i & 7)) << 3) + (k & 7);
    sWth[off] = hh; sWtl[off] = ll;
  }
  for (int idx = tid; idx < 1024; idx += NT) {
    int k = idx >> 4, u = idx & 15;
    unsigned short hh, ll;
    f2hl(Bb[idx], hh, ll);
    int off = u * 64 + (((k >> 3) ^ (u & 7)) << 3) + (k & 7);
    sVBh[off] = hh; sVBl[off] = ll;
  }
  __syncthreads();

  // ---- S2: hoist loop-invariant fragments to registers ----
  bf16x8 afYh[4][2], afYl[4][2];   // At rows 16c+r (Y-operand for W=V*A, Atv)
  bf16x8 atfh[2], atfl[2];         // At rows 16it+r (X-operand for A^T W)
  bf16x8 btfh[2], btfl[2];         // Bt rows r
  #pragma unroll
  for (int kc = 0; kc < 2; ++kc) {
    #pragma unroll
    for (int c = 0; c < 4; ++c) {
      afYh[c][kc] = ld64(sWth, 16 * c + r, 4 * kc + g);
      afYl[c][kc] = ld64(sWtl, 16 * c + r, 4 * kc + g);
    }
    atfh[kc] = ld64(sWth, 16 * it + r, 4 * kc + g);
    atfl[kc] = ld64(sWtl, 16 * it + r, 4 * kc + g);
    btfh[kc] = ld64(sVBh, r, 4 * kc + g);
    btfl[kc] = ld64(sVBl, r, 4 * kc + g);
  }
  __syncthreads();

  // ---- S3: stage V(=Q) h/l; goals -> sWt rows 0..31 ----
  for (int idx = tid; idx < 4096; idx += NT) {
    int k = idx >> 6, i = idx & 63;
    unsigned short hh, ll;
    f2hl(Qb[idx], hh, ll);
    int off = k * 64 + (((i >> 3) ^ (k & 7)) << 3) + (i & 7);
    sVh[off] = hh; sVl[off] = ll;
  }
  for (int idx = tid; idx < 2048; idx += NT) {
    int tg = idx >> 6, k = idx & 63;
    float val = (tg <= TH) ? Gb[idx] : 0.f;
    unsigned short hh, ll;
    f2hl(val, hh, ll);
    int off = tg * 64 + (((k >> 3) ^ (tg & 7)) << 3) + (k & 7);
    sWth[off] = hh; sWtl[off] = ll;
  }
  __syncthreads();

  // ---- S4: QG via MFMA -> stash; v0 -> sv ----
  {
    const int tt = wv >> 1;
    #pragma unroll
    for (int ci = 0; ci < 2; ++ci) {
      const int ic = 2 * (wv & 1) + ci;
      f32x4 acc = {};
      #pragma unroll
      for (int kc = 0; kc < 2; ++kc) {
        int kcg = 4 * kc + g;
        bf16x8 xh = ld64(sWth, 16 * tt + r, kcg);
        bf16x8 xl = ld64(sWtl, 16 * tt + r, kcg);
        bf16x8 yh = ld64(sVh, 16 * ic + r, kcg);
        bf16x8 yl = ld64(sVl, 16 * ic + r, kcg);
        MFMA3(acc, xh, xl, yh, yl)
      }
      #pragma unroll
      for (int rg = 0; rg < 4; ++rg) {
        int t2 = 16 * tt + 4 * g + rg;
        int i2 = 16 * ic + r;
        if (t2 < TH) gQG[((size_t)t2 * bsz + b) * qgSlot + i2] = acc[rg];
        else if (t2 == TH) sv[i2] = acc[rg];
      }
    }
  }
  __syncthreads();

  float wt_ = 0.f;   // w~ = M*Btv on w3 lanes<16 (P_D -> P_E)

  #pragma unroll 1
  for (int t = TH - 1; t >= 0; --t) {
    const size_t obase = ((size_t)t * bsz + b) * 1040;
    float qgt = 0.f;
    if (wv == 3) qgt = gQG[((size_t)t * bsz + b) * qgSlot + lane];
    f32x4 vacc[4];
    #pragma unroll
    for (int c = 0; c < 4; ++c) {
      #pragma unroll
      for (int rg = 0; rg < 4; ++rg)
        vacc[c][rg] = Qb[(16 * it + 4 * g + rg) * 64 + 16 * c + r];  // L3-hot
    }

    auto ATW = [&](int kc) {   // vacc[c] += (A^T W) subtiles (it, c)
      const int kcg = 4 * kc + g;
      #pragma unroll
      for (int c = 0; c < 4; ++c) {
        bf16x8 yh = ld64(sWth, 16 * c + r, kcg);
        bf16x8 yl = ld64(sWtl, 16 * c + r, kcg);
        MFMA3(vacc[c], atfh[kc], atfl[kc], yh, yl)
      }
    };
    auto mkv = [&](int kc, bf16x8& vh, bf16x8& vl) {  // broadcast-v frag (row 0)
      vh = bf16x8{}; vl = bf16x8{};
      if (r == 0) {
        #pragma unroll
        for (int e = 0; e < 8; ++e) {
          unsigned short hh, ll;
          f2hl(sv[32 * kc + 8 * g + e], hh, ll);
          vh[e] = (short)hh; vl[e] = (short)ll;
        }
      }
    };

    // ===== P_A: W = V*A (A from regs); VB = V*B =====
    {
      f32x4 aW[4] = {}, aVB = {};
      #pragma unroll
      for (int kc = 0; kc < 2; ++kc) {
        int kcg = 4 * kc + g;
        bf16x8 xh = ld64(sVh, 16 * it + r, kcg);
        bf16x8 xl = ld64(sVl, 16 * it + r, kcg);
        #pragma unroll
        for (int c = 0; c < 4; ++c) {
          MFMA3(aW[c], xh, xl, afYh[c][kc], afYl[c][kc])
        }
        MFMA3(aVB, xh, xl, btfh[kc], btfl[kc])
      }
      u16x4 h4, l4;
      #pragma unroll
      for (int c = 0; c < 4; ++c) {
        cvt4(aW[c], h4, l4);
        st64_4(sWth, 16 * c + r, 16 * it + 4 * g, h4);
        st64_4(sWtl, 16 * c + r, 16 * it + 4 * g, l4);
      }
      cvt4(aVB, h4, l4);
      st64_4(sVBh, r, 16 * it + 4 * g, h4);
      st64_4(sVBl, r, 16 * it + 4 * g, l4);
    }
    __syncthreads();

    // ===== P_B: Vuu+Btv (w0) | BtW x2 (w1,w2) | Atv (w3) ; w0-2 + ATW(0) =====
    if (wv == 0) {
      f32x4 accU, accBv = {};
      #pragma unroll
      for (int rg = 0; rg < 4; ++rg) accU[rg] = Rb[(4 * g + rg) * 16 + r];
      #pragma unroll
      for (int kc = 0; kc < 2; ++kc) {
        int kcg = 4 * kc + g;
        bf16x8 yh = ld64(sVBh, r, kcg);
        bf16x8 yl = ld64(sVBl, r, kcg);
        MFMA3(accU, btfh[kc], btfl[kc], yh, yl)
        bf16x8 vh, vl; mkv(kc, vh, vl);
        MFMA3(accBv, btfh[kc], btfl[kc], vh, vl)
      }
      #pragma unroll
      for (int rg = 0; rg < 4; ++rg) sVuu[(4 * g + rg) * 17 + r] = accU[rg];
      if (r == 0) {
        #pragma unroll
        for (int rg = 0; rg < 4; ++rg) sBtv[4 * g + rg] = accBv[rg];
      }
    } else if (wv <= 2) {
      #pragma unroll
      for (int ci = 0; ci < 2; ++ci) {
        const int c = 2 * (wv - 1) + ci;
        f32x4 acc = {};
        #pragma unroll
        for (int kc = 0; kc < 2; ++kc) {
          bf16x8 yh = ld64(sWth, 16 * c + r, 4 * kc + g);
          bf16x8 yl = ld64(sWtl, 16 * c + r, 4 * kc + g);
          MFMA3(acc, btfh[kc], btfl[kc], yh, yl)
        }
        u16x4 h4, l4; cvt4(acc, h4, l4);
        st16s(sBWh, 16 * c + r, 4 * g, h4);
        st16s(sBWl, 16 * c + r, 4 * g, l4);
      }
    } else if (t > 0) {  // w3: Atv via Y-frags (all row-tiles)
      f32x4 at0 = {}, at1 = {}, at2 = {}, at3 = {};
      #pragma unroll
      for (int kc = 0; kc < 2; ++kc) {
        bf16x8 vh, vl; mkv(kc, vh, vl);
        MFMA3(at0, vh, vl, afYh[0][kc], afYl[0][kc])
        MFMA3(at1, vh, vl, afYh[1][kc], afYl[1][kc])
        MFMA3(at2, vh, vl, afYh[2][kc], afYl[2][kc])
        MFMA3(at3, vh, vl, afYh[3][kc], afYl[3][kc])
      }
      if (g == 0) {  // D[0][r] lives on g==0, reg 0
        sVp[r]      = at0[0];
        sVp[16 + r] = at1[0];
        sVp[32 + r] = at2[0];
        sVp[48 + r] = at3[0];
      }
    }
    if (wv != 3 && t > 0) ATW(0);
    __syncthreads();

    // ===== P_C: chol+M (w0) | ATW(1) (w1,w2) | ATW(0)+ATW(1) (w3) =====
    if (wv == 0) {
      const int u = r;
      float rr[16];
      #pragma unroll
      for (int k = 0; k < 16; ++k) rr[k] = sVuu[u * 17 + k];
      #pragma unroll
      for (int j = 0; j < 16; ++j) {
        float s = rr[j];
        #pragma unroll
        for (int k = 0; k < j; ++k) s -= rr[k] * __shfl(rr[k], j);
        const float dj  = sqrtf(__shfl(s, j));
        const float inv = 1.f / dj;
        rr[j] = (u == j) ? dj : s * inv;
      }
      float x[16];
      #pragma unroll
      for (int i = 0; i < 16; ++i) {
        float s = (i == u) ? 1.f : 0.f;
        #pragma unroll
        for (int k = 0; k < i; ++k) s -= __shfl(rr[k], i) * x[k];
        x[i] = s / __shfl(rr[i], i);
      }
      if (lane < 16) {   // lane u holds column u of M = L^{-1}: x[i] = M[i][u]
        #pragma unroll
        for (int i = 0; i < 16; ++i) {
          sMT[u * 17 + i] = x[i];
          unsigned short hh, ll;
          f2hl(x[i], hh, ll);
          sMth[u * 16 + i] = hh; sMtl[u * 16 + i] = ll;  // Mt[u][i]=M[i][u]
          sMbh[i * 16 + u] = hh; sMbl[i * 16 + u] = ll;  // Mb[i][u]=M[i][u]
        }
      }
    } else if (t > 0) {
      ATW(1);
      if (wv == 3) ATW(0);
    }
    __syncthreads();

    // ===== P_D: per-wave c-tile: S = M*BtW (in-place), Kg = M^T*S -> gOut; w3: kg =====
    {
      const int c = wv;
      f32x4 sacc = {};
      {
        bf16x8 xh = ld16s(sMbh, r, g), xl = ld16s(sMbl, r, g);
        bf16x8 yh = ld16s(sBWh, 16 * c + r, g), yl = ld16s(sBWl, 16 * c + r, g);
        MFMA3(sacc, xh, xl, yh, yl)          // D[u][j] = S[u][j]
      }
      u16x4 h4, l4; cvt4(sacc, h4, l4);
      st16s(sBWh, 16 * c + r, 4 * g, h4);    // St[j][u] over BtW (own rows only)
      st16s(sBWl, 16 * c + r, 4 * g, l4);
      f32x4 kacc = {};
      {
        bf16x8 xh = ld16s(sMth, r, g), xl = ld16s(sMtl, r, g);
        bf16x8 yh = ld16s(sBWh, 16 * c + r, g), yl = ld16s(sBWl, 16 * c + r, g);
        MFMA3(kacc, xh, xl, yh, yl)          // D[u][j] = Kg[u][j]
      }
      #pragma unroll
      for (int rg = 0; rg < 4; ++rg)
        gOut[obase + (size_t)(4 * g + rg) * 65 + 16 * c + r] = kacc[rg];
      if (wv == 3 && lane < 16) {
        wt_ = 0.f;
        #pragma unroll
        for (int u2 = 0; u2 < 16; ++u2)
          wt_ += sMT[u2 * 17 + lane] * sBtv[u2];          // w~ = M Btv
        float kgv = 0.f;
        #pragma unroll
        for (int w2 = 0; w2 < 16; ++w2)
          kgv += __shfl(wt_, w2) * sMT[lane * 17 + w2];   // kg = M^T w~
        gOut[obase + (size_t)lane * 65 + 64] = kgv;
      }
    }
    __syncthreads();

    // ===== P_E: Vnew = Q + A^T W - S^T S -> sV; w0: +ATW(1); w3: v update =====
    if (t > 0) {
      if (wv == 0) ATW(1);
      bf16x8 xnh = negbf(ld16s(sBWh, 16 * it + r, g));
      bf16x8 xnl = negbf(ld16s(sBWl, 16 * it + r, g));
      u16x4 h4, l4;
      #pragma unroll
      for (int c = 0; c < 4; ++c) {
        bf16x8 yh = ld16s(sBWh, 16 * c + r, g);
        bf16x8 yl = ld16s(sBWl, 16 * c + r, g);
        MFMA3(vacc[c], xnh, xnl, yh, yl)
        cvt4(vacc[c], h4, l4);
        st64_4(sVh, 16 * c + r, 16 * it + 4 * g, h4);
        st64_4(sVl, 16 * c + r, 16 * it + 4 * g, l4);
      }
      if (wv == 3) {
        const int i = lane;
        float s = qgt + sVp[i];
        #pragma unroll
        for (int u2 = 0; u2 < 16; ++u2)
          s -= rec(sBWh[i * 16 + u2], sBWl[i * 16 + u2]) * __shfl(wt_, u2);
        sv[i] = s;   // v_new = qg + A^T v - S^T w~
      }
    }
    __syncthreads();
  }
}

extern "C" void kernel_launch(void* const* d_in, const int* in_sizes, int n_in,
                              void* d_out, int out_size, void* d_ws, size_t ws_size,
                              hipStream_t stream) {
  (void)n_in; (void)out_size;
  const float* A = (const float*)d_in[0];
  const float* B = (const float*)d_in[1];
  const float* Q = (const float*)d_in[2];
  const float* R = (const float*)d_in[3];
  const float* G = (const float*)d_in[4];
  float* out = (float*)d_out;
  const int bsz = in_sizes[3] / 256;   // R is bsz*16*16
  const size_t need = (size_t)bsz * TH * 64 * sizeof(float);
  float* qg   = (ws_size >= need) ? (float*)d_ws : out;
  int qgSlot  = (ws_size >= need) ? 64 : 1040;
  lqr6<<<bsz, NT, 0, stream>>>(A, B, Q, R, G, out, qg, qgSlot, bsz);
}

// Round 9
// 1355.385 us; speedup vs baseline: 1.2006x; 1.2006x over previous
//
#include <hip/hip_runtime.h>

#define TH 30
#define NT 256

typedef short bf16x8 __attribute__((ext_vector_type(8)));
typedef float f32x4 __attribute__((ext_vector_type(4)));
typedef unsigned short u16x4 __attribute__((ext_vector_type(4)));
typedef unsigned int u32x4 __attribute__((ext_vector_type(4)));

// split f into bf16 hi + bf16 lo (truncation; lo compensates) ~2^-17 rel
__device__ __forceinline__ void f2hl(float f, unsigned short& h, unsigned short& l) {
  unsigned int ub = __float_as_uint(f);
  h = (unsigned short)(ub >> 16);
  float fh = __uint_as_float(ub & 0xffff0000u);
  l = (unsigned short)(__float_as_uint(f - fh) >> 16);
}
__device__ __forceinline__ float rec(unsigned short h, unsigned short l) {
  return __uint_as_float((unsigned int)h << 16) + __uint_as_float((unsigned int)l << 16);
}
// [R][64] ushort, granule-swizzled: (r,k) at r*64 + (((k>>3)^(r&7))<<3) + (k&7)
__device__ __forceinline__ bf16x8 ld64(const unsigned short* buf, int row, int kcg) {
  return *(const bf16x8*)(buf + row * 64 + ((kcg ^ (row & 7)) << 3));
}
__device__ __forceinline__ void st64_4(unsigned short* buf, int row, int col0, u16x4 v) {
  *(u16x4*)(buf + row * 64 + (((col0 >> 3) ^ (row & 7)) << 3) + (col0 & 7)) = v;
}
__device__ __forceinline__ void st64_1(unsigned short* buf, int row, int col, unsigned short v) {
  buf[row * 64 + ((((col >> 3)) ^ (row & 7)) << 3) + (col & 7)] = v;
}
// K=16 tiles, stride 16; g>=2 -> zero frags (K padding)
__device__ __forceinline__ bf16x8 ld16s(const unsigned short* buf, int row, int g) {
  if (g < 2) return *(const bf16x8*)(buf + row * 16 + (g << 3));
  bf16x8 z = {};
  return z;
}
__device__ __forceinline__ void st16s(unsigned short* buf, int row, int col0, u16x4 v) {
  *(u16x4*)(buf + row * 16 + col0) = v;
}
__device__ __forceinline__ void cvt4(f32x4 a, u16x4& h, u16x4& l) {
  #pragma unroll
  for (int i = 0; i < 4; ++i) {
    unsigned short hh, ll;
    f2hl(a[i], hh, ll);
    h[i] = hh; l[i] = ll;
  }
}
__device__ __forceinline__ bf16x8 negbf(bf16x8 v) {
  u32x4 u = __builtin_bit_cast(u32x4, v);
  u ^= 0x80008000u;
  return __builtin_bit_cast(bf16x8, u);
}

#define MFMA3(ACC, XH, XL, YH, YL)                                        \
  ACC = __builtin_amdgcn_mfma_f32_16x16x32_bf16(XH, YH, ACC, 0, 0, 0);    \
  ACC = __builtin_amdgcn_mfma_f32_16x16x32_bf16(XH, YL, ACC, 0, 0, 0);    \
  ACC = __builtin_amdgcn_mfma_f32_16x16x32_bf16(XL, YH, ACC, 0, 0, 0);

// LDS plan (bytes; total 45760 -> 3 blocks/CU, verified by r7 occupancy 31.4%)
#define O_VH   0       /* 8192  V hi (sym), swz */
#define O_VL   8192    /* 8192  V lo */
#define O_WTH  16384   /* 8192  Wt hi, swz (init: At staging, then goals rows 0..31) */
#define O_WTL  24576   /* 8192  Wt lo */
#define O_VBH  32768   /* 2048  VBt hi (init: Bt staging) */
#define O_VBL  34816   /* 2048  VBt lo */
#define O_BWH  36864   /* 2048  BtWt hi; St in-place */
#define O_BWL  38912   /* 2048  lo */
#define O_MTH  40960   /* 512   Mt[u][i]=M[i][u] hi */
#define O_MTL  41472
#define O_MBH  41984   /* 512   Mb[u][w]=M[u][w] hi */
#define O_MBL  42496
#define O_VUU  43008   /* f32 16x17 */
#define O_MT   44096   /* f32 16x17 */
#define O_VP   45184   /* f32 64  A^T v */
#define O_SV   45440   /* f32 64  v */
#define O_BTV  45696   /* f32 16  B^T v */
#define SMEM_BYTES 45760

__global__ __launch_bounds__(NT, 3) void lqr9(
    const float* __restrict__ gA, const float* __restrict__ gB,
    const float* __restrict__ gQ, const float* __restrict__ gR,
    const float* __restrict__ gG, float* __restrict__ gOut,
    float* __restrict__ gQG, int qgSlot, int bsz)
{
  __shared__ __align__(16) unsigned char smem[SMEM_BYTES];
  unsigned short* sVh  = (unsigned short*)(smem + O_VH);
  unsigned short* sVl  = (unsigned short*)(smem + O_VL);
  unsigned short* sWth = (unsigned short*)(smem + O_WTH);
  unsigned short* sWtl = (unsigned short*)(smem + O_WTL);
  unsigned short* sVBh = (unsigned short*)(smem + O_VBH);
  unsigned short* sVBl = (unsigned short*)(smem + O_VBL);
  unsigned short* sBWh = (unsigned short*)(smem + O_BWH);
  unsigned short* sBWl = (unsigned short*)(smem + O_BWL);
  unsigned short* sMth = (unsigned short*)(smem + O_MTH);
  unsigned short* sMtl = (unsigned short*)(smem + O_MTL);
  unsigned short* sMbh = (unsigned short*)(smem + O_MBH);
  unsigned short* sMbl = (unsigned short*)(smem + O_MBL);
  float* sVuu = (float*)(smem + O_VUU);
  float* sMT  = (float*)(smem + O_MT);
  float* sVp  = (float*)(smem + O_VP);
  float* sv   = (float*)(smem + O_SV);
  float* sBtv = (float*)(smem + O_BTV);

  const int b    = blockIdx.x;
  const int tid  = threadIdx.x;
  const int lane = tid & 63;
  const int wv   = tid >> 6;      // 0..3
  const int r    = lane & 15;
  const int g    = lane >> 4;
  const int it   = wv;            // owned row-tile

  const float* Ab = gA + (size_t)b * 4096;
  const float* Bb = gB + (size_t)b * 1024;
  const float* Qb = gQ + (size_t)b * 4096;
  const float* Rb = gR + (size_t)b * 256;
  const float* Gb = gG + (size_t)b * ((TH + 1) * 64);

  // ---- S1: stage At h/l -> sWt (temp), Bt h/l -> sVB (temp) ----
  for (int idx = tid; idx < 4096; idx += NT) {
    int k = idx >> 6, i = idx & 63;
    unsigned short hh, ll;
    f2hl(Ab[idx], hh, ll);
    int off = i * 64 + (((k >> 3) ^ (i & 7)) << 3) + (k & 7);
    sWth[off] = hh; sWtl[off] = ll;
  }
  for (int idx = tid; idx < 1024; idx += NT) {
    int k = idx >> 4, u = idx & 15;
    unsigned short hh, ll;
    f2hl(Bb[idx], hh, ll);
    int off = u * 64 + (((k >> 3) ^ (u & 7)) << 3) + (k & 7);
    sVBh[off] = hh; sVBl[off] = ll;
  }
  __syncthreads();

  // ---- S2: hoist loop-invariant fragments (no afY; ~52 persistent VGPR) ----
  bf16x8 atfh[2], atfl[2];   // At rows 16it+r (X-operand everywhere)
  bf16x8 btfh[2], btfl[2];   // Bt rows r
  #pragma unroll
  for (int kc = 0; kc < 2; ++kc) {
    atfh[kc] = ld64(sWth, 16 * it + r, 4 * kc + g);
    atfl[kc] = ld64(sWtl, 16 * it + r, 4 * kc + g);
    btfh[kc] = ld64(sVBh, r, 4 * kc + g);
    btfl[kc] = ld64(sVBl, r, 4 * kc + g);
  }
  f32x4 qreg[4], rreg;
  #pragma unroll
  for (int c = 0; c < 4; ++c) {
    #pragma unroll
    for (int rg = 0; rg < 4; ++rg)
      qreg[c][rg] = Qb[(16 * it + 4 * g + rg) * 64 + 16 * c + r];
  }
  #pragma unroll
  for (int rg = 0; rg < 4; ++rg) rreg[rg] = Rb[(4 * g + rg) * 16 + r];
  __syncthreads();

  // ---- S3: stage V(=Q) h/l; goals -> sWt rows 0..31 ----
  for (int idx = tid; idx < 4096; idx += NT) {
    int k = idx >> 6, i = idx & 63;
    unsigned short hh, ll;
    f2hl(Qb[idx], hh, ll);
    int off = k * 64 + (((i >> 3) ^ (k & 7)) << 3) + (i & 7);
    sVh[off] = hh; sVl[off] = ll;
  }
  for (int idx = tid; idx < 2048; idx += NT) {
    int tg = idx >> 6, k = idx & 63;
    float val = (tg <= TH) ? Gb[idx] : 0.f;
    unsigned short hh, ll;
    f2hl(val, hh, ll);
    int off = tg * 64 + (((k >> 3) ^ (tg & 7)) << 3) + (k & 7);
    sWth[off] = hh; sWtl[off] = ll;
  }
  __syncthreads();

  // ---- S4: QG via MFMA -> stash; v0 -> sv ----
  {
    const int tt = wv >> 1;
    #pragma unroll
    for (int ci = 0; ci < 2; ++ci) {
      const int ic = 2 * (wv & 1) + ci;
      f32x4 acc = {};
      #pragma unroll
      for (int kc = 0; kc < 2; ++kc) {
        int kcg = 4 * kc + g;
        bf16x8 xh = ld64(sWth, 16 * tt + r, kcg);
        bf16x8 xl = ld64(sWtl, 16 * tt + r, kcg);
        bf16x8 yh = ld64(sVh, 16 * ic + r, kcg);
        bf16x8 yl = ld64(sVl, 16 * ic + r, kcg);
        MFMA3(acc, xh, xl, yh, yl)
      }
      #pragma unroll
      for (int rg = 0; rg < 4; ++rg) {
        int t2 = 16 * tt + 4 * g + rg;
        int i2 = 16 * ic + r;
        if (t2 < TH) gQG[((size_t)t2 * bsz + b) * qgSlot + i2] = acc[rg];
        else if (t2 == TH) sv[i2] = acc[rg];
      }
    }
  }
  __syncthreads();

  float wt_ = 0.f;   // w~ = M*Btv on w3 lanes<16 (P_D -> P_E)

  #pragma unroll 1
  for (int t = TH - 1; t >= 0; --t) {
    const size_t obase = ((size_t)t * bsz + b) * 1040;
    float qgt = 0.f;
    if (wv == 3) qgt = gQG[((size_t)t * bsz + b) * qgSlot + lane];
    f32x4 vacc[4];
    #pragma unroll
    for (int c = 0; c < 4; ++c) vacc[c] = qreg[c];

    auto ATW = [&](int kc) {   // vacc[c] += (A^T W): X=atf, Y=Wt rows (c-tile)
      const int kcg = 4 * kc + g;
      #pragma unroll
      for (int c = 0; c < 4; ++c) {
        bf16x8 yh = ld64(sWth, 16 * c + r, kcg);
        bf16x8 yl = ld64(sWtl, 16 * c + r, kcg);
        MFMA3(vacc[c], atfh[kc], atfl[kc], yh, yl)
      }
    };
    auto mkv = [&](int kc, bf16x8& vh, bf16x8& vl) {  // broadcast-v frag (Y row 0)
      vh = bf16x8{}; vl = bf16x8{};
      if (r == 0) {
        #pragma unroll
        for (int e = 0; e < 8; ++e) {
          unsigned short hh, ll;
          f2hl(sv[32 * kc + 8 * g + e], hh, ll);
          vh[e] = (short)hh; vl[e] = (short)ll;
        }
      }
    };

    // ===== P_A: Wt[own j-rows][all i] = (A^T V) via X=atf, Y=sV; VBt via X=sV own rows =====
    {
      f32x4 aW[4] = {}, aVB = {};
      #pragma unroll
      for (int kc = 0; kc < 2; ++kc) {
        int kcg = 4 * kc + g;
        bf16x8 xvh, xvl;
        #pragma unroll
        for (int c = 0; c < 4; ++c) {
          bf16x8 yvh = ld64(sVh, 16 * c + r, kcg);
          bf16x8 yvl = ld64(sVl, 16 * c + r, kcg);
          MFMA3(aW[c], atfh[kc], atfl[kc], yvh, yvl)   // D[j'][i'] = Wt
          if (c == it) { xvh = yvh; xvl = yvl; }
        }
        MFMA3(aVB, xvh, xvl, btfh[kc], btfl[kc])       // D[i'][u] (own i-tile)
      }
      u16x4 h4, l4;
      #pragma unroll
      for (int c = 0; c < 4; ++c) {   // scalar stores: row 16it+4g+rg, col 16c+r
        cvt4(aW[c], h4, l4);
        #pragma unroll
        for (int rg = 0; rg < 4; ++rg) {
          st64_1(sWth, 16 * it + 4 * g + rg, 16 * c + r, h4[rg]);
          st64_1(sWtl, 16 * it + 4 * g + rg, 16 * c + r, l4[rg]);
        }
      }
      cvt4(aVB, h4, l4);              // vector store: VBt[u=r][cols 16it+4g..]
      st64_4(sVBh, r, 16 * it + 4 * g, h4);
      st64_4(sVBl, r, 16 * it + 4 * g, l4);
    }
    __syncthreads();

    // ===== P_B: all: Atv own rows | w0: Vuu+Btv | w1,w2: BtW x2 | w3: ATW(0) =====
    if (t > 0) {
      f32x4 at = {};
      #pragma unroll
      for (int kc = 0; kc < 2; ++kc) {
        bf16x8 vh, vl; mkv(kc, vh, vl);
        MFMA3(at, atfh[kc], atfl[kc], vh, vl)   // D[i'][0] on lanes r==0
      }
      if (r == 0) {
        #pragma unroll
        for (int rg = 0; rg < 4; ++rg) sVp[16 * it + 4 * g + rg] = at[rg];
      }
    }
    if (wv == 0) {
      f32x4 accU = rreg, accBv = {};
      #pragma unroll
      for (int kc = 0; kc < 2; ++kc) {
        int kcg = 4 * kc + g;
        bf16x8 yh = ld64(sVBh, r, kcg);
        bf16x8 yl = ld64(sVBl, r, kcg);
        MFMA3(accU, btfh[kc], btfl[kc], yh, yl)   // D[u][w] = Vuu
        bf16x8 vh, vl; mkv(kc, vh, vl);           // Btv needed at EVERY t (kg output)
        MFMA3(accBv, btfh[kc], btfl[kc], vh, vl)
      }
      #pragma unroll
      for (int rg = 0; rg < 4; ++rg) sVuu[(4 * g + rg) * 17 + r] = accU[rg];
      if (r == 0) {
        #pragma unroll
        for (int rg = 0; rg < 4; ++rg) sBtv[4 * g + rg] = accBv[rg];
      }
    } else if (wv <= 2) {
      #pragma unroll
      for (int ci = 0; ci < 2; ++ci) {
        const int c = 2 * (wv - 1) + ci;
        f32x4 acc = {};
        #pragma unroll
        for (int kc = 0; kc < 2; ++kc) {
          bf16x8 yh = ld64(sWth, 16 * c + r, 4 * kc + g);
          bf16x8 yl = ld64(sWtl, 16 * c + r, 4 * kc + g);
          MFMA3(acc, btfh[kc], btfl[kc], yh, yl)   // D[u][j] = BtW
        }
        u16x4 h4, l4; cvt4(acc, h4, l4);
        st16s(sBWh, 16 * c + r, 4 * g, h4);        // BWt[j][u]
        st16s(sBWl, 16 * c + r, 4 * g, l4);
      }
    } else if (t > 0) {
      ATW(0);
    }
    __syncthreads();

    // ===== P_C: chol+M (w0) | ATW full (w1,w2) | ATW(1) (w3) =====
    if (wv == 0) {
      const int u = r;
      float rr[16];
      #pragma unroll
      for (int k = 0; k < 16; ++k) rr[k] = sVuu[u * 17 + k];
      #pragma unroll
      for (int j = 0; j < 16; ++j) {
        float s = rr[j];
        #pragma unroll
        for (int k = 0; k < j; ++k) s -= rr[k] * __shfl(rr[k], j);
        const float dj  = sqrtf(__shfl(s, j));
        const float inv = 1.f / dj;
        rr[j] = (u == j) ? dj : s * inv;
      }
      float x[16];
      #pragma unroll
      for (int i = 0; i < 16; ++i) {
        float s = (i == u) ? 1.f : 0.f;
        #pragma unroll
        for (int k = 0; k < i; ++k) s -= __shfl(rr[k], i) * x[k];
        x[i] = s / __shfl(rr[i], i);
      }
      if (lane < 16) {   // lane u holds column u of M = L^{-1}: x[i] = M[i][u]
        #pragma unroll
        for (int i = 0; i < 16; ++i) {
          sMT[u * 17 + i] = x[i];
          unsigned short hh, ll;
          f2hl(x[i], hh, ll);
          sMth[u * 16 + i] = hh; sMtl[u * 16 + i] = ll;  // Mt[u][i]=M[i][u]
          sMbh[i * 16 + u] = hh; sMbl[i * 16 + u] = ll;  // Mb[i][u]=M[i][u]
        }
      }
    } else if (t > 0) {
      ATW(1);
      if (wv <= 2) ATW(0);
    }
    __syncthreads();

    // ===== P_D: S=M*BtW in-place + Kg -> gOut (w1: c01, w2: c23) | kg (w3) | ATW (w0) =====
    if (wv == 0) {
      if (t > 0) { ATW(0); ATW(1); }
    } else if (wv <= 2) {
      #pragma unroll
      for (int ci = 0; ci < 2; ++ci) {
        const int c = 2 * (wv - 1) + ci;
        f32x4 sacc = {};
        {
          bf16x8 xh = ld16s(sMbh, r, g), xl = ld16s(sMbl, r, g);
          bf16x8 yh = ld16s(sBWh, 16 * c + r, g), yl = ld16s(sBWl, 16 * c + r, g);
          MFMA3(sacc, xh, xl, yh, yl)          // D[u][j] = S[u][j]
        }
        u16x4 h4, l4; cvt4(sacc, h4, l4);
        st16s(sBWh, 16 * c + r, 4 * g, h4);    // St[j][u] over BtW (own rows)
        st16s(sBWl, 16 * c + r, 4 * g, l4);
        f32x4 kacc = {};
        {
          bf16x8 xh = ld16s(sMth, r, g), xl = ld16s(sMtl, r, g);
          bf16x8 yh = ld16s(sBWh, 16 * c + r, g), yl = ld16s(sBWl, 16 * c + r, g);
          MFMA3(kacc, xh, xl, yh, yl)          // D[u][j] = Kg[u][j]
        }
        #pragma unroll
        for (int rg = 0; rg < 4; ++rg)
          gOut[obase + (size_t)(4 * g + rg) * 65 + 16 * c + r] = kacc[rg];
      }
    } else if (lane < 16) {
      wt_ = 0.f;
      #pragma unroll
      for (int u2 = 0; u2 < 16; ++u2)
        wt_ += sMT[u2 * 17 + lane] * sBtv[u2];          // w~ = M Btv
      float kgv = 0.f;
      #pragma unroll
      for (int w2 = 0; w2 < 16; ++w2)
        kgv += __shfl(wt_, w2) * sMT[lane * 17 + w2];   // kg = M^T w~
      gOut[obase + (size_t)lane * 65 + 64] = kgv;
    }
    __syncthreads();

    // ===== P_E: Vnew = Q + A^T W - S^T S -> sV (transposed store, V sym); w3: v =====
    if (t > 0) {
      bf16x8 xnh = negbf(ld16s(sBWh, 16 * it + r, g));
      bf16x8 xnl = negbf(ld16s(sBWl, 16 * it + r, g));
      u16x4 h4, l4;
      #pragma unroll
      for (int c = 0; c < 4; ++c) {
        bf16x8 yh = ld16s(sBWh, 16 * c + r, g);
        bf16x8 yl = ld16s(sBWl, 16 * c + r, g);
        MFMA3(vacc[c], xnh, xnl, yh, yl)
        cvt4(vacc[c], h4, l4);
        st64_4(sVh, 16 * c + r, 16 * it + 4 * g, h4);
        st64_4(sVl, 16 * c + r, 16 * it + 4 * g, l4);
      }
      if (wv == 3) {
        const int i = lane;
        float s = qgt + sVp[i];
        #pragma unroll
        for (int u2 = 0; u2 < 16; ++u2)
          s -= rec(sBWh[i * 16 + u2], sBWl[i * 16 + u2]) * __shfl(wt_, u2);
        sv[i] = s;   // v_new = qg + A^T v - S^T w~
      }
    }
    __syncthreads();
  }
}

extern "C" void kernel_launch(void* const* d_in, const int* in_sizes, int n_in,
                              void* d_out, int out_size, void* d_ws, size_t ws_size,
                              hipStream_t stream) {
  (void)n_in; (void)out_size;
  const float* A = (const float*)d_in[0];
  const float* B = (const float*)d_in[1];
  const float* Q = (const float*)d_in[2];
  const float* R = (const float*)d_in[3];
  const float* G = (const float*)d_in[4];
  float* out = (float*)d_out;
  const int bsz = in_sizes[3] / 256;   // R is bsz*16*16
  const size_t need = (size_t)bsz * TH * 64 * sizeof(float);
  float* qg   = (ws_size >= need) ? (float*)d_ws : out;
  int qgSlot  = (ws_size >= need) ? 64 : 1040;
  lqr9<<<bsz, NT, 0, stream>>>(A, B, Q, R, G, out, qg, qgSlot, bsz);
}

// Round 10
// 1171.661 us; speedup vs baseline: 1.3889x; 1.1568x over previous
//
#include <hip/hip_runtime.h>

#define TH 30
#define NT 256

typedef short bf16x8 __attribute__((ext_vector_type(8)));
typedef float f32x4 __attribute__((ext_vector_type(4)));
typedef unsigned short u16x4 __attribute__((ext_vector_type(4)));
typedef unsigned int u32x4 __attribute__((ext_vector_type(4)));

// split f into bf16 hi + bf16 lo (truncation; lo compensates) ~2^-17 rel
__device__ __forceinline__ void f2hl(float f, unsigned short& h, unsigned short& l) {
  unsigned int ub = __float_as_uint(f);
  h = (unsigned short)(ub >> 16);
  float fh = __uint_as_float(ub & 0xffff0000u);
  l = (unsigned short)(__float_as_uint(f - fh) >> 16);
}
__device__ __forceinline__ float rec(unsigned short h, unsigned short l) {
  return __uint_as_float((unsigned int)h << 16) + __uint_as_float((unsigned int)l << 16);
}
// [R][64] ushort, granule-swizzled: (r,k) at r*64 + (((k>>3)^(r&7))<<3) + (k&7)
__device__ __forceinline__ bf16x8 ld64(const unsigned short* buf, int row, int kcg) {
  return *(const bf16x8*)(buf + row * 64 + ((kcg ^ (row & 7)) << 3));
}
__device__ __forceinline__ void st64_4(unsigned short* buf, int row, int col0, u16x4 v) {
  *(u16x4*)(buf + row * 64 + (((col0 >> 3) ^ (row & 7)) << 3) + (col0 & 7)) = v;
}
__device__ __forceinline__ void st64_1(unsigned short* buf, int row, int col, unsigned short v) {
  buf[row * 64 + ((((col >> 3)) ^ (row & 7)) << 3) + (col & 7)] = v;
}
// K=16 tiles, stride 16; g>=2 -> zero frags (K padding)
__device__ __forceinline__ bf16x8 ld16s(const unsigned short* buf, int row, int g) {
  if (g < 2) return *(const bf16x8*)(buf + row * 16 + (g << 3));
  bf16x8 z = {};
  return z;
}
__device__ __forceinline__ void st16s(unsigned short* buf, int row, int col0, u16x4 v) {
  *(u16x4*)(buf + row * 16 + col0) = v;
}
__device__ __forceinline__ void cvt4(f32x4 a, u16x4& h, u16x4& l) {
  #pragma unroll
  for (int i = 0; i < 4; ++i) {
    unsigned short hh, ll;
    f2hl(a[i], hh, ll);
    h[i] = hh; l[i] = ll;
  }
}
__device__ __forceinline__ bf16x8 negbf(bf16x8 v) {
  u32x4 u = __builtin_bit_cast(u32x4, v);
  u ^= 0x80008000u;
  return __builtin_bit_cast(bf16x8, u);
}

#define MFMA3(ACC, XH, XL, YH, YL)                                        \
  ACC = __builtin_amdgcn_mfma_f32_16x16x32_bf16(XH, YH, ACC, 0, 0, 0);    \
  ACC = __builtin_amdgcn_mfma_f32_16x16x32_bf16(XH, YL, ACC, 0, 0, 0);    \
  ACC = __builtin_amdgcn_mfma_f32_16x16x32_bf16(XL, YH, ACC, 0, 0, 0);

// LDS plan (bytes; total 45760 -> 3 blocks/CU, verified r7/r9 occupancy 31.4%)
#define O_VH   0       /* 8192  V hi (sym), swz */
#define O_VL   8192    /* 8192  V lo */
#define O_WTH  16384   /* 8192  Wt hi, swz (init: At staging, then goals rows 0..31) */
#define O_WTL  24576   /* 8192  Wt lo */
#define O_VBH  32768   /* 2048  VBt hi (init: Bt staging) */
#define O_VBL  34816   /* 2048  VBt lo */
#define O_BWH  36864   /* 2048  BtWt hi; St in-place */
#define O_BWL  38912   /* 2048  lo */
#define O_MTH  40960   /* 512   Mt[u][i]=M[i][u] hi */
#define O_MTL  41472
#define O_MBH  41984   /* 512   Mb[u][w]=M[u][w] hi */
#define O_MBL  42496
#define O_VUU  43008   /* f32 16x17 */
#define O_MT   44096   /* f32 16x17  sMT[u][i]=M[i][u] */
#define O_VP   45184   /* f32 64  A^T v */
#define O_SV   45440   /* f32 64  v */
#define O_BTV  45696   /* f32 16  B^T v */
#define SMEM_BYTES 45760

__global__ __launch_bounds__(NT, 3) void lqr10(
    const float* __restrict__ gA, const float* __restrict__ gB,
    const float* __restrict__ gQ, const float* __restrict__ gR,
    const float* __restrict__ gG, float* __restrict__ gOut,
    float* __restrict__ gQG, int qgSlot, int bsz)
{
  __shared__ __align__(16) unsigned char smem[SMEM_BYTES];
  unsigned short* sVh  = (unsigned short*)(smem + O_VH);
  unsigned short* sVl  = (unsigned short*)(smem + O_VL);
  unsigned short* sWth = (unsigned short*)(smem + O_WTH);
  unsigned short* sWtl = (unsigned short*)(smem + O_WTL);
  unsigned short* sVBh = (unsigned short*)(smem + O_VBH);
  unsigned short* sVBl = (unsigned short*)(smem + O_VBL);
  unsigned short* sBWh = (unsigned short*)(smem + O_BWH);
  unsigned short* sBWl = (unsigned short*)(smem + O_BWL);
  unsigned short* sMth = (unsigned short*)(smem + O_MTH);
  unsigned short* sMtl = (unsigned short*)(smem + O_MTL);
  unsigned short* sMbh = (unsigned short*)(smem + O_MBH);
  unsigned short* sMbl = (unsigned short*)(smem + O_MBL);
  float* sVuu = (float*)(smem + O_VUU);
  float* sMT  = (float*)(smem + O_MT);
  float* sVp  = (float*)(smem + O_VP);
  float* sv   = (float*)(smem + O_SV);
  float* sBtv = (float*)(smem + O_BTV);

  const int b    = blockIdx.x;
  const int tid  = threadIdx.x;
  const int lane = tid & 63;
  const int wv   = tid >> 6;      // 0..3
  const int r    = lane & 15;
  const int g    = lane >> 4;
  const int it   = wv;            // owned row-tile

  const float* Ab = gA + (size_t)b * 4096;
  const float* Bb = gB + (size_t)b * 1024;
  const float* Qb = gQ + (size_t)b * 4096;
  const float* Rb = gR + (size_t)b * 256;
  const float* Gb = gG + (size_t)b * ((TH + 1) * 64);

  // ---- S1: stage At h/l -> sWt (temp), Bt h/l -> sVB (temp) ----
  for (int idx = tid; idx < 4096; idx += NT) {
    int k = idx >> 6, i = idx & 63;
    unsigned short hh, ll;
    f2hl(Ab[idx], hh, ll);
    int off = i * 64 + (((k >> 3) ^ (i & 7)) << 3) + (k & 7);
    sWth[off] = hh; sWtl[off] = ll;
  }
  for (int idx = tid; idx < 1024; idx += NT) {
    int k = idx >> 4, u = idx & 15;
    unsigned short hh, ll;
    f2hl(Bb[idx], hh, ll);
    int off = u * 64 + (((k >> 3) ^ (u & 7)) << 3) + (k & 7);
    sVBh[off] = hh; sVBl[off] = ll;
  }
  __syncthreads();

  // ---- S2: hoist ONLY A/B fragments (32 persistent VGPR; Q/R reload from L2) ----
  bf16x8 atfh[2], atfl[2];   // At rows 16it+r (X-operand everywhere)
  bf16x8 btfh[2], btfl[2];   // Bt rows r
  #pragma unroll
  for (int kc = 0; kc < 2; ++kc) {
    atfh[kc] = ld64(sWth, 16 * it + r, 4 * kc + g);
    atfl[kc] = ld64(sWtl, 16 * it + r, 4 * kc + g);
    btfh[kc] = ld64(sVBh, r, 4 * kc + g);
    btfl[kc] = ld64(sVBl, r, 4 * kc + g);
  }
  __syncthreads();

  // ---- S3: stage V(=Q) h/l; goals -> sWt rows 0..31 ----
  for (int idx = tid; idx < 4096; idx += NT) {
    int k = idx >> 6, i = idx & 63;
    unsigned short hh, ll;
    f2hl(Qb[idx], hh, ll);
    int off = k * 64 + (((i >> 3) ^ (k & 7)) << 3) + (i & 7);
    sVh[off] = hh; sVl[off] = ll;
  }
  for (int idx = tid; idx < 2048; idx += NT) {
    int tg = idx >> 6, k = idx & 63;
    float val = (tg <= TH) ? Gb[idx] : 0.f;
    unsigned short hh, ll;
    f2hl(val, hh, ll);
    int off = tg * 64 + (((k >> 3) ^ (tg & 7)) << 3) + (k & 7);
    sWth[off] = hh; sWtl[off] = ll;
  }
  __syncthreads();

  // ---- S4: QG via MFMA -> stash; v0 -> sv ----
  {
    const int tt = wv >> 1;
    #pragma unroll
    for (int ci = 0; ci < 2; ++ci) {
      const int ic = 2 * (wv & 1) + ci;
      f32x4 acc = {};
      #pragma unroll
      for (int kc = 0; kc < 2; ++kc) {
        int kcg = 4 * kc + g;
        bf16x8 xh = ld64(sWth, 16 * tt + r, kcg);
        bf16x8 xl = ld64(sWtl, 16 * tt + r, kcg);
        bf16x8 yh = ld64(sVh, 16 * ic + r, kcg);
        bf16x8 yl = ld64(sVl, 16 * ic + r, kcg);
        MFMA3(acc, xh, xl, yh, yl)
      }
      #pragma unroll
      for (int rg = 0; rg < 4; ++rg) {
        int t2 = 16 * tt + 4 * g + rg;
        int i2 = 16 * ic + r;
        if (t2 < TH) gQG[((size_t)t2 * bsz + b) * qgSlot + i2] = acc[rg];
        else if (t2 == TH) sv[i2] = acc[rg];
      }
    }
  }
  __syncthreads();

  float wt_ = 0.f;   // w~ = M*Btv on w3 lanes<16 (P_D -> P_E)

  #pragma unroll 1
  for (int t = TH - 1; t >= 0; --t) {
    const size_t obase = ((size_t)t * bsz + b) * 1040;
    float qgt = 0.f;
    if (wv == 3) qgt = gQG[((size_t)t * bsz + b) * qgSlot + lane];
    f32x4 vacc[4];   // initialized in the wave's ATW phase only (short lifetime)

    auto vaccQ = [&]() {   // vacc[c] = Q subtile (L2-hot reload, replaces qreg)
      #pragma unroll
      for (int c = 0; c < 4; ++c) {
        #pragma unroll
        for (int rg = 0; rg < 4; ++rg)
          vacc[c][rg] = Qb[(16 * it + 4 * g + rg) * 64 + 16 * c + r];
      }
    };
    auto ATW = [&](int kc) {   // vacc[c] += (A^T W): X=atf, Y=Wt rows (c-tile)
      const int kcg = 4 * kc + g;
      #pragma unroll
      for (int c = 0; c < 4; ++c) {
        bf16x8 yh = ld64(sWth, 16 * c + r, kcg);
        bf16x8 yl = ld64(sWtl, 16 * c + r, kcg);
        MFMA3(vacc[c], atfh[kc], atfl[kc], yh, yl)
      }
    };
    auto mkv = [&](int kc, bf16x8& vh, bf16x8& vl) {  // broadcast-v frag (Y row 0)
      vh = bf16x8{}; vl = bf16x8{};
      if (r == 0) {
        #pragma unroll
        for (int e = 0; e < 8; ++e) {
          unsigned short hh, ll;
          f2hl(sv[32 * kc + 8 * g + e], hh, ll);
          vh[e] = (short)hh; vl[e] = (short)ll;
        }
      }
    };

    // ===== P_A: Wt[own j-rows][all i] = (A^T V) via X=atf, Y=sV; VBt own i-tile =====
    {
      f32x4 aW[4] = {}, aVB = {};
      #pragma unroll
      for (int kc = 0; kc < 2; ++kc) {
        int kcg = 4 * kc + g;
        bf16x8 xvh, xvl;
        #pragma unroll
        for (int c = 0; c < 4; ++c) {
          bf16x8 yvh = ld64(sVh, 16 * c + r, kcg);
          bf16x8 yvl = ld64(sVl, 16 * c + r, kcg);
          MFMA3(aW[c], atfh[kc], atfl[kc], yvh, yvl)   // D[j'][i'] = Wt
          if (c == it) { xvh = yvh; xvl = yvl; }
        }
        MFMA3(aVB, xvh, xvl, btfh[kc], btfl[kc])       // D[i'][u] (own i-tile)
      }
      u16x4 h4, l4;
      #pragma unroll
      for (int c = 0; c < 4; ++c) {   // scalar stores: row 16it+4g+rg, col 16c+r
        cvt4(aW[c], h4, l4);
        #pragma unroll
        for (int rg = 0; rg < 4; ++rg) {
          st64_1(sWth, 16 * it + 4 * g + rg, 16 * c + r, h4[rg]);
          st64_1(sWtl, 16 * it + 4 * g + rg, 16 * c + r, l4[rg]);
        }
      }
      cvt4(aVB, h4, l4);              // vector store: VBt[u=r][cols 16it+4g..]
      st64_4(sVBh, r, 16 * it + 4 * g, h4);
      st64_4(sVBl, r, 16 * it + 4 * g, l4);
    }
    __syncthreads();

    // ===== P_B: all: Atv own rows | w0: Vuu+Btv | w1: BtW c01 | w2: c2 | w3: c3 =====
    if (t > 0) {
      f32x4 at = {};
      #pragma unroll
      for (int kc = 0; kc < 2; ++kc) {
        bf16x8 vh, vl; mkv(kc, vh, vl);
        MFMA3(at, atfh[kc], atfl[kc], vh, vl)   // D[i'][0] on lanes r==0
      }
      if (r == 0) {
        #pragma unroll
        for (int rg = 0; rg < 4; ++rg) sVp[16 * it + 4 * g + rg] = at[rg];
      }
    }
    if (wv == 0) {
      f32x4 accU, accBv = {};
      #pragma unroll
      for (int rg = 0; rg < 4; ++rg) accU[rg] = Rb[(4 * g + rg) * 16 + r];  // L2-hot
      #pragma unroll
      for (int kc = 0; kc < 2; ++kc) {
        int kcg = 4 * kc + g;
        bf16x8 yh = ld64(sVBh, r, kcg);
        bf16x8 yl = ld64(sVBl, r, kcg);
        MFMA3(accU, btfh[kc], btfl[kc], yh, yl)   // D[u][w] = Vuu
        bf16x8 vh, vl; mkv(kc, vh, vl);           // Btv needed at EVERY t (kg)
        MFMA3(accBv, btfh[kc], btfl[kc], vh, vl)
      }
      #pragma unroll
      for (int rg = 0; rg < 4; ++rg) sVuu[(4 * g + rg) * 17 + r] = accU[rg];
      if (r == 0) {
        #pragma unroll
        for (int rg = 0; rg < 4; ++rg) sBtv[4 * g + rg] = accBv[rg];
      }
    } else if (wv == 1) {
      #pragma unroll
      for (int ci = 0; ci < 2; ++ci) {
        const int c = ci;
        f32x4 acc = {};
        #pragma unroll
        for (int kc = 0; kc < 2; ++kc) {
          bf16x8 yh = ld64(sWth, 16 * c + r, 4 * kc + g);
          bf16x8 yl = ld64(sWtl, 16 * c + r, 4 * kc + g);
          MFMA3(acc, btfh[kc], btfl[kc], yh, yl)   // D[u][j] = BtW
        }
        u16x4 h4, l4; cvt4(acc, h4, l4);
        st16s(sBWh, 16 * c + r, 4 * g, h4);        // BWt[j][u]
        st16s(sBWl, 16 * c + r, 4 * g, l4);
      }
    } else {
      const int c = wv;   // w2 -> c2, w3 -> c3
      f32x4 acc = {};
      #pragma unroll
      for (int kc = 0; kc < 2; ++kc) {
        bf16x8 yh = ld64(sWth, 16 * c + r, 4 * kc + g);
        bf16x8 yl = ld64(sWtl, 16 * c + r, 4 * kc + g);
        MFMA3(acc, btfh[kc], btfl[kc], yh, yl)
      }
      u16x4 h4, l4; cvt4(acc, h4, l4);
      st16s(sBWh, 16 * c + r, 4 * g, h4);
      st16s(sBWl, 16 * c + r, 4 * g, l4);
    }
    __syncthreads();

    // ===== P_C: chol+M (w0, x via LDS) | w1-3: vacc=Q; ATW(0)+ATW(1) =====
    if (wv == 0) {
      const int u = r;
      float rr[16];
      #pragma unroll
      for (int k = 0; k < 16; ++k) rr[k] = sVuu[u * 17 + k];
      #pragma unroll
      for (int j = 0; j < 16; ++j) {
        float s = rr[j];
        #pragma unroll
        for (int k = 0; k < j; ++k) s -= rr[k] * __shfl(rr[k], j);
        const float dj  = sqrtf(__shfl(s, j));
        const float inv = 1.f / dj;
        rr[j] = (u == j) ? dj : s * inv;
      }
      // forward-substitution: column u of M = L^{-1}, x[k] staged in sMT (LDS)
      if (lane < 16) {
        #pragma unroll
        for (int i = 0; i < 16; ++i) {
          float s = (i == u) ? 1.f : 0.f;
          #pragma unroll
          for (int k = 0; k < i; ++k) s -= __shfl(rr[k], i) * sMT[u * 17 + k];
          const float xi = s / __shfl(rr[i], i);
          sMT[u * 17 + i] = xi;
          unsigned short hh, ll;
          f2hl(xi, hh, ll);
          sMth[u * 16 + i] = hh; sMtl[u * 16 + i] = ll;  // Mt[u][i]=M[i][u]
          sMbh[i * 16 + u] = hh; sMbl[i * 16 + u] = ll;  // Mb[i][u]=M[i][u]
        }
      }
    } else if (t > 0) {
      vaccQ();
      ATW(0);
      ATW(1);
    }
    __syncthreads();

    // ===== P_D: w0: vacc=Q+ATW | w1: S/Kg c01 | w2: c23 | w3: kg =====
    if (wv == 0) {
      if (t > 0) { vaccQ(); ATW(0); ATW(1); }
    } else if (wv <= 2) {
      #pragma unroll
      for (int ci = 0; ci < 2; ++ci) {
        const int c = 2 * (wv - 1) + ci;
        f32x4 sacc = {};
        {
          bf16x8 xh = ld16s(sMbh, r, g), xl = ld16s(sMbl, r, g);
          bf16x8 yh = ld16s(sBWh, 16 * c + r, g), yl = ld16s(sBWl, 16 * c + r, g);
          MFMA3(sacc, xh, xl, yh, yl)          // D[u][j] = S[u][j]
        }
        u16x4 h4, l4; cvt4(sacc, h4, l4);
        st16s(sBWh, 16 * c + r, 4 * g, h4);    // St[j][u] over BtW (own rows)
        st16s(sBWl, 16 * c + r, 4 * g, l4);
        f32x4 kacc = {};
        {
          bf16x8 xh = ld16s(sMth, r, g), xl = ld16s(sMtl, r, g);
          bf16x8 yh = ld16s(sBWh, 16 * c + r, g), yl = ld16s(sBWl, 16 * c + r, g);
          MFMA3(kacc, xh, xl, yh, yl)          // D[u][j] = Kg[u][j]
        }
        #pragma unroll
        for (int rg = 0; rg < 4; ++rg)
          gOut[obase + (size_t)(4 * g + rg) * 65 + 16 * c + r] = kacc[rg];
      }
    } else if (lane < 16) {
      wt_ = 0.f;
      #pragma unroll
      for (int u2 = 0; u2 < 16; ++u2)
        wt_ += sMT[u2 * 17 + lane] * sBtv[u2];          // w~ = M Btv
      float kgv = 0.f;
      #pragma unroll
      for (int w2 = 0; w2 < 16; ++w2)
        kgv += __shfl(wt_, w2) * sMT[lane * 17 + w2];   // kg = M^T w~
      gOut[obase + (size_t)lane * 65 + 64] = kgv;
    }
    __syncthreads();

    // ===== P_E: Vnew = (Q + A^T W) - S^T S -> sV (transposed, V sym); w3: v =====
    if (t > 0) {
      bf16x8 xnh = negbf(ld16s(sBWh, 16 * it + r, g));
      bf16x8 xnl = negbf(ld16s(sBWl, 16 * it + r, g));
      u16x4 h4, l4;
      #pragma unroll
      for (int c = 0; c < 4; ++c) {
        bf16x8 yh = ld16s(sBWh, 16 * c + r, g);
        bf16x8 yl = ld16s(sBWl, 16 * c + r, g);
        MFMA3(vacc[c], xnh, xnl, yh, yl)
        cvt4(vacc[c], h4, l4);
        st64_4(sVh, 16 * c + r, 16 * it + 4 * g, h4);
        st64_4(sVl, 16 * c + r, 16 * it + 4 * g, l4);
      }
      if (wv == 3) {
        const int i = lane;
        float s = qgt + sVp[i];
        #pragma unroll
        for (int u2 = 0; u2 < 16; ++u2)
          s -= rec(sBWh[i * 16 + u2], sBWl[i * 16 + u2]) * __shfl(wt_, u2);
        sv[i] = s;   // v_new = qg + A^T v - S^T w~
      }
    }
    __syncthreads();
  }
}

extern "C" void kernel_launch(void* const* d_in, const int* in_sizes, int n_in,
                              void* d_out, int out_size, void* d_ws, size_t ws_size,
                              hipStream_t stream) {
  (void)n_in; (void)out_size;
  const float* A = (const float*)d_in[0];
  const float* B = (const float*)d_in[1];
  const float* Q = (const float*)d_in[2];
  const float* R = (const float*)d_in[3];
  const float* G = (const float*)d_in[4];
  float* out = (float*)d_out;
  const int bsz = in_sizes[3] / 256;   // R is bsz*16*16
  const size_t need = (size_t)bsz * TH * 64 * sizeof(float);
  float* qg   = (ws_size >= need) ? (float*)d_ws : out;
  int qgSlot  = (ws_size >= need) ? 64 : 1040;
  lqr10<<<bsz, NT, 0, stream>>>(A, B, Q, R, G, out, qg, qgSlot, bsz);
}